// Round 1
// baseline (210.470 us; speedup 1.0000x reference)
//
#include <hip/hip_runtime.h>

#define SEQ 2048
#define DIM 1280
#define NH 16
#define HD 80

typedef __attribute__((ext_vector_type(8))) short short8;
typedef __attribute__((ext_vector_type(4))) float f32x4;

__device__ inline unsigned short f2bf(float f) {
  unsigned u = __builtin_bit_cast(unsigned, f);
  u += 0x7FFFu + ((u >> 16) & 1u);
  return (unsigned short)(u >> 16);
}
__device__ inline float bf2f(unsigned short h) {
  unsigned u = ((unsigned)h) << 16;
  return __builtin_bit_cast(float, u);
}

// ---------------- f32 -> bf16 conversion ----------------
__global__ void cvt_f32_bf16(const float* __restrict__ src,
                             unsigned short* __restrict__ dst, int n) {
  int i = (blockIdx.x * 256 + threadIdx.x) * 4;
  if (i >= n) return;
  float4 v = *(const float4*)(src + i);
  dst[i + 0] = f2bf(v.x);
  dst[i + 1] = f2bf(v.y);
  dst[i + 2] = f2bf(v.z);
  dst[i + 3] = f2bf(v.w);
}

// ---------------- GEMM core: C[M,N] = A[M,K] * B[N,K]^T + bias ----------------
// 128x128 tile, BK=32, 4 waves (2x2 of 64x64), 4x4 fragments of 16x16x32 bf16
template <int OUTMODE>  // 0 = bf16 out, 1 = f32 out
__device__ void gemm_core(const unsigned short* __restrict__ A,
                          const unsigned short* __restrict__ B,
                          const float* __restrict__ bias, void* __restrict__ Cout,
                          int M, int N, int K) {
  __shared__ unsigned short As[128][56];  // pad 32 -> 56 (112B stride, 16B-aligned, 2-way banks)
  __shared__ unsigned short Bs[128][56];
  const int tid = threadIdx.x;
  const int wave = tid >> 6;
  const int lane = tid & 63;
  const int wr = (wave >> 1) * 64, wc = (wave & 1) * 64;
  const int bm = blockIdx.x * 128, bn = blockIdx.y * 128;
  const int lrow = lane & 15, lgrp = lane >> 4;

  f32x4 acc[4][4] = {};

  const int sr = tid >> 2;         // 0..63
  const int sc = (tid & 3) * 8;    // 0,8,16,24

  for (int k0 = 0; k0 < K; k0 += 32) {
    __syncthreads();
    short8 a0 = *(const short8*)(A + (long)(bm + sr) * K + k0 + sc);
    short8 a1 = *(const short8*)(A + (long)(bm + sr + 64) * K + k0 + sc);
    short8 b0 = *(const short8*)(B + (long)(bn + sr) * K + k0 + sc);
    short8 b1 = *(const short8*)(B + (long)(bn + sr + 64) * K + k0 + sc);
    *(short8*)&As[sr][sc] = a0;
    *(short8*)&As[sr + 64][sc] = a1;
    *(short8*)&Bs[sr][sc] = b0;
    *(short8*)&Bs[sr + 64][sc] = b1;
    __syncthreads();

    short8 af[4], bfr[4];
#pragma unroll
    for (int i = 0; i < 4; i++)
      af[i] = *(const short8*)&As[wr + i * 16 + lrow][lgrp * 8];
#pragma unroll
    for (int j = 0; j < 4; j++)
      bfr[j] = *(const short8*)&Bs[wc + j * 16 + lrow][lgrp * 8];
#pragma unroll
    for (int i = 0; i < 4; i++)
#pragma unroll
      for (int j = 0; j < 4; j++)
        acc[i][j] = __builtin_amdgcn_mfma_f32_16x16x32_bf16(af[i], bfr[j], acc[i][j], 0, 0, 0);
  }

#pragma unroll
  for (int i = 0; i < 4; i++) {
    int row = bm + wr + i * 16 + lgrp * 4;
#pragma unroll
    for (int j = 0; j < 4; j++) {
      int col = bn + wc + j * 16 + lrow;
      float bv = bias[col];
#pragma unroll
      for (int r = 0; r < 4; r++) {
        float v = acc[i][j][r] + bv;
        if (OUTMODE == 0)
          ((unsigned short*)Cout)[(long)(row + r) * N + col] = f2bf(v);
        else
          ((float*)Cout)[(long)(row + r) * N + col] = v;
      }
    }
  }
}

__global__ __launch_bounds__(256) void gemm_qkv(
    const unsigned short* __restrict__ A, const unsigned short* __restrict__ Bq,
    const unsigned short* __restrict__ Bk, const unsigned short* __restrict__ Bv,
    const float* __restrict__ bq, const float* __restrict__ bk,
    const float* __restrict__ bv, unsigned short* __restrict__ Cq,
    unsigned short* __restrict__ Ck, unsigned short* __restrict__ Cv) {
  int z = blockIdx.z;
  const unsigned short* B = z == 0 ? Bq : (z == 1 ? Bk : Bv);
  const float* bias = z == 0 ? bq : (z == 1 ? bk : bv);
  unsigned short* C = z == 0 ? Cq : (z == 1 ? Ck : Cv);
  gemm_core<0>(A, B, bias, C, SEQ, DIM, DIM);
}

__global__ __launch_bounds__(256) void gemm_out(
    const unsigned short* __restrict__ A, const unsigned short* __restrict__ B,
    const float* __restrict__ bias, float* __restrict__ C) {
  gemm_core<1>(A, B, bias, C, SEQ, DIM, DIM);
}

// ---------------- RoPE (in place on bf16 Q,K) ----------------
__global__ void rope_kernel(unsigned short* __restrict__ Q,
                            unsigned short* __restrict__ Kt,
                            const float* __restrict__ cosT,
                            const float* __restrict__ sinT) {
  int idx = blockIdx.x * 256 + threadIdx.x;
  if (idx >= SEQ * NH * 40) return;
  int j = idx % 40;
  int t = idx / 40;
  int h = t & 15;
  int s = t >> 4;
  long base = (long)s * DIM + h * HD;
  float c0 = cosT[s * HD + j], s0 = sinT[s * HD + j];
  float c1 = cosT[s * HD + j + 40], s1 = sinT[s * HD + j + 40];
  float q0 = bf2f(Q[base + j]), q1 = bf2f(Q[base + j + 40]);
  Q[base + j] = f2bf(q0 * c0 - q1 * s0);
  Q[base + j + 40] = f2bf(q1 * c1 + q0 * s1);
  float k0 = bf2f(Kt[base + j]), k1 = bf2f(Kt[base + j + 40]);
  Kt[base + j] = f2bf(k0 * c0 - k1 * s0);
  Kt[base + j + 40] = f2bf(k1 * c1 + k0 * s1);
}

// ---------------- Flash attention over block-diagonal segments ----------------
// block = (head h, segment g, 64-row q tile); 4 waves, wave owns 16 q rows.
__global__ __launch_bounds__(256) void attn_kernel(
    const unsigned short* __restrict__ Q, const unsigned short* __restrict__ K,
    const unsigned short* __restrict__ V, unsigned short* __restrict__ O,
    const int* __restrict__ cu) {
  const int h = blockIdx.x;
  const int g = blockIdx.y;
  const int qt = blockIdx.z;
  const int s0 = cu[g], s1 = cu[g + 1];
  const int qbase = s0 + qt * 64;
  if (qbase >= s1) return;

  __shared__ unsigned short q_s[64][104];   // 64 x 96 used (hd padded to 96), stride pad
  __shared__ unsigned short k_s[64][104];
  __shared__ unsigned short vt_s[80][72];   // V^T: [d][key]
  __shared__ unsigned short p_s[4][16][72]; // per-wave P tile [qrow][key]

  const int tid = threadIdx.x;
  const int wave = tid >> 6, lane = tid & 63;
  const int lrow = lane & 15, lgrp = lane >> 4;

  // stage Q tile (zero-pad cols 80..95)
  for (int idx = tid; idx < 64 * 96; idx += 256) {
    int r = idx / 96, c = idx % 96;
    int srow = qbase + r;
    unsigned short v = 0;
    if (c < HD && srow < s1) v = Q[(long)srow * DIM + h * HD + c];
    q_s[r][c] = v;
  }
  __syncthreads();

  short8 aq[3];
#pragma unroll
  for (int ks = 0; ks < 3; ks++)
    aq[ks] = *(const short8*)&q_s[wave * 16 + lrow][ks * 32 + lgrp * 8];

  f32x4 o_acc[5] = {};
  float m_r[4], l_r[4];
#pragma unroll
  for (int r = 0; r < 4; r++) { m_r[r] = -1e30f; l_r[r] = 0.f; }

  const float scale = 0.11180339887498949f;  // 1/sqrt(80)

  const int nk = (s1 - s0 + 63) / 64;
  for (int ck = 0; ck < nk; ck++) {
    const int kb = s0 + ck * 64;
    __syncthreads();
    for (int idx = tid; idx < 64 * 96; idx += 256) {
      int r = idx / 96, c = idx % 96;
      int srow = kb + r;
      unsigned short v = 0;
      if (c < HD && srow < s1) v = K[(long)srow * DIM + h * HD + c];
      k_s[r][c] = v;
    }
    for (int idx = tid; idx < 80 * 64; idx += 256) {
      int d = idx >> 6, kk = idx & 63;
      int srow = kb + kk;
      unsigned short v = 0;
      if (srow < s1) v = V[(long)srow * DIM + h * HD + d];
      vt_s[d][kk] = v;
    }
    __syncthreads();

    // S = Q K^T for this wave's 16 rows x 64 keys
    f32x4 s_acc[4] = {};
#pragma unroll
    for (int n = 0; n < 4; n++)
#pragma unroll
      for (int ks = 0; ks < 3; ks++) {
        short8 bk8 = *(const short8*)&k_s[n * 16 + lrow][ks * 32 + lgrp * 8];
        s_acc[n] = __builtin_amdgcn_mfma_f32_16x16x32_bf16(aq[ks], bk8, s_acc[n], 0, 0, 0);
      }

    float sv[4][4];
#pragma unroll
    for (int n = 0; n < 4; n++) {
      int key = kb + n * 16 + lrow;
      bool valid = key < s1;
#pragma unroll
      for (int r = 0; r < 4; r++)
        sv[n][r] = valid ? s_acc[n][r] * scale : -1e30f;
    }
    float mx[4];
#pragma unroll
    for (int r = 0; r < 4; r++) {
      float m = fmaxf(fmaxf(sv[0][r], sv[1][r]), fmaxf(sv[2][r], sv[3][r]));
      m = fmaxf(m, __shfl_xor(m, 1));
      m = fmaxf(m, __shfl_xor(m, 2));
      m = fmaxf(m, __shfl_xor(m, 4));
      m = fmaxf(m, __shfl_xor(m, 8));
      mx[r] = m;
    }
    float p[4][4];
#pragma unroll
    for (int r = 0; r < 4; r++) {
      float mnew = fmaxf(m_r[r], mx[r]);
      float sc = __expf(m_r[r] - mnew);
      float rs = 0.f;
#pragma unroll
      for (int n = 0; n < 4; n++) {
        float pv = __expf(sv[n][r] - mnew);
        p[n][r] = pv;
        rs += pv;
      }
      rs += __shfl_xor(rs, 1);
      rs += __shfl_xor(rs, 2);
      rs += __shfl_xor(rs, 4);
      rs += __shfl_xor(rs, 8);
      l_r[r] = l_r[r] * sc + rs;
      m_r[r] = mnew;
#pragma unroll
      for (int nf = 0; nf < 5; nf++) o_acc[nf][r] *= sc;
    }
#pragma unroll
    for (int n = 0; n < 4; n++)
#pragma unroll
      for (int r = 0; r < 4; r++)
        p_s[wave][lgrp * 4 + r][n * 16 + lrow] = f2bf(p[n][r]);
    __syncthreads();
#pragma unroll
    for (int ks = 0; ks < 2; ks++) {
      short8 pa = *(const short8*)&p_s[wave][lrow][ks * 32 + lgrp * 8];
#pragma unroll
      for (int nf = 0; nf < 5; nf++) {
        short8 bv8 = *(const short8*)&vt_s[nf * 16 + lrow][ks * 32 + lgrp * 8];
        o_acc[nf] = __builtin_amdgcn_mfma_f32_16x16x32_bf16(pa, bv8, o_acc[nf], 0, 0, 0);
      }
    }
  }

#pragma unroll
  for (int r = 0; r < 4; r++) {
    int row = qbase + wave * 16 + lgrp * 4 + r;
    if (row < s1) {
      float inv = 1.0f / l_r[r];
#pragma unroll
      for (int nf = 0; nf < 5; nf++)
        O[(long)row * DIM + h * HD + nf * 16 + lrow] = f2bf(o_acc[nf][r] * inv);
    }
  }
}

extern "C" void kernel_launch(void* const* d_in, const int* in_sizes, int n_in,
                              void* d_out, int out_size, void* d_ws, size_t ws_size,
                              hipStream_t stream) {
  const float* hs = (const float*)d_in[0];
  const float* Wq = (const float*)d_in[1];
  const float* bq = (const float*)d_in[2];
  const float* Wk = (const float*)d_in[3];
  const float* bk = (const float*)d_in[4];
  const float* Wv = (const float*)d_in[5];
  const float* bv = (const float*)d_in[6];
  const float* Wo = (const float*)d_in[7];
  const float* bo = (const float*)d_in[8];
  const float* cosT = (const float*)d_in[9];
  const float* sinT = (const float*)d_in[10];
  const int* cu = (const int*)d_in[11];
  const int nseg = in_sizes[11] - 1;  // 4

  char* ws = (char*)d_ws;
  unsigned short* hs_b = (unsigned short*)(ws);
  unsigned short* wq_b = (unsigned short*)(ws + 5242880);
  unsigned short* wk_b = (unsigned short*)(ws + 8519680);
  unsigned short* wv_b = (unsigned short*)(ws + 11796480);
  unsigned short* wo_b = (unsigned short*)(ws + 15073280);
  unsigned short* q_b  = (unsigned short*)(ws + 18350080);
  unsigned short* k_b  = (unsigned short*)(ws + 23592960);
  unsigned short* v_b  = (unsigned short*)(ws + 28835840);
  unsigned short* ao_b = (unsigned short*)(ws + 34078720);

  const int nh = SEQ * DIM;   // 2621440
  const int nw = DIM * DIM;   // 1638400
  cvt_f32_bf16<<<nh / 1024, 256, 0, stream>>>(hs, hs_b, nh);
  cvt_f32_bf16<<<nw / 1024, 256, 0, stream>>>(Wq, wq_b, nw);
  cvt_f32_bf16<<<nw / 1024, 256, 0, stream>>>(Wk, wk_b, nw);
  cvt_f32_bf16<<<nw / 1024, 256, 0, stream>>>(Wv, wv_b, nw);
  cvt_f32_bf16<<<nw / 1024, 256, 0, stream>>>(Wo, wo_b, nw);

  dim3 gq(SEQ / 128, DIM / 128, 3);
  gemm_qkv<<<gq, 256, 0, stream>>>(hs_b, wq_b, wk_b, wv_b, bq, bk, bv, q_b, k_b, v_b);

  rope_kernel<<<(SEQ * NH * 40) / 256, 256, 0, stream>>>(q_b, k_b, cosT, sinT);

  dim3 ga(NH, nseg, (SEQ / nseg + 63) / 64);
  attn_kernel<<<ga, 256, 0, stream>>>(q_b, k_b, v_b, ao_b, cu);

  dim3 go(SEQ / 128, DIM / 128, 1);
  gemm_out<<<go, 256, 0, stream>>>(ao_b, wo_b, bo, (float*)d_out);
}

// Round 2
// 128.634 us; speedup vs baseline: 1.6362x; 1.6362x over previous
//
#include <hip/hip_runtime.h>

#define SEQ 2048
#define DIM 1280
#define NH 16
#define HD 80

typedef __attribute__((ext_vector_type(8))) short short8;
typedef __attribute__((ext_vector_type(4))) float f32x4;

__device__ inline unsigned short f2bf(float f) {
  unsigned u = __builtin_bit_cast(unsigned, f);
  u += 0x7FFFu + ((u >> 16) & 1u);
  return (unsigned short)(u >> 16);
}
__device__ inline float bf2f(unsigned short h) {
  unsigned u = ((unsigned)h) << 16;
  return __builtin_bit_cast(float, u);
}

// ---------------- f32 -> bf16 conversion ----------------
__global__ void cvt_f32_bf16(const float* __restrict__ src,
                             unsigned short* __restrict__ dst, int n) {
  int i = (blockIdx.x * 256 + threadIdx.x) * 4;
  if (i >= n) return;
  float4 v = *(const float4*)(src + i);
  dst[i + 0] = f2bf(v.x);
  dst[i + 1] = f2bf(v.y);
  dst[i + 2] = f2bf(v.z);
  dst[i + 3] = f2bf(v.w);
}

// 4 weights in one launch: blockIdx.y selects source; dst contiguous
__global__ void cvt_w4(const float* __restrict__ w0, const float* __restrict__ w1,
                       const float* __restrict__ w2, const float* __restrict__ w3,
                       unsigned short* __restrict__ dst, int nw) {
  int which = blockIdx.y;
  const float* src = which == 0 ? w0 : (which == 1 ? w1 : (which == 2 ? w2 : w3));
  int i = (blockIdx.x * 256 + threadIdx.x) * 4;
  if (i >= nw) return;
  float4 v = *(const float4*)(src + i);
  unsigned short* d = dst + (long)which * nw + i;
  d[0] = f2bf(v.x);
  d[1] = f2bf(v.y);
  d[2] = f2bf(v.z);
  d[3] = f2bf(v.w);
}

// ---------------- GEMM core: C[M,N] = A[M,K] * B[N,K]^T + bias ----------------
template <int OUTMODE>  // 0 = bf16 out, 1 = f32 out
__device__ void gemm_core(const unsigned short* __restrict__ A,
                          const unsigned short* __restrict__ B,
                          const float* __restrict__ bias, void* __restrict__ Cout,
                          int M, int N, int K) {
  __shared__ unsigned short As[128][56];
  __shared__ unsigned short Bs[128][56];
  const int tid = threadIdx.x;
  const int wave = tid >> 6;
  const int lane = tid & 63;
  const int wr = (wave >> 1) * 64, wc = (wave & 1) * 64;
  const int bm = blockIdx.x * 128, bn = blockIdx.y * 128;
  const int lrow = lane & 15, lgrp = lane >> 4;

  f32x4 acc[4][4] = {};

  const int sr = tid >> 2;
  const int sc = (tid & 3) * 8;

  for (int k0 = 0; k0 < K; k0 += 32) {
    __syncthreads();
    short8 a0 = *(const short8*)(A + (long)(bm + sr) * K + k0 + sc);
    short8 a1 = *(const short8*)(A + (long)(bm + sr + 64) * K + k0 + sc);
    short8 b0 = *(const short8*)(B + (long)(bn + sr) * K + k0 + sc);
    short8 b1 = *(const short8*)(B + (long)(bn + sr + 64) * K + k0 + sc);
    *(short8*)&As[sr][sc] = a0;
    *(short8*)&As[sr + 64][sc] = a1;
    *(short8*)&Bs[sr][sc] = b0;
    *(short8*)&Bs[sr + 64][sc] = b1;
    __syncthreads();

    short8 af[4], bfr[4];
#pragma unroll
    for (int i = 0; i < 4; i++)
      af[i] = *(const short8*)&As[wr + i * 16 + lrow][lgrp * 8];
#pragma unroll
    for (int j = 0; j < 4; j++)
      bfr[j] = *(const short8*)&Bs[wc + j * 16 + lrow][lgrp * 8];
#pragma unroll
    for (int i = 0; i < 4; i++)
#pragma unroll
      for (int j = 0; j < 4; j++)
        acc[i][j] = __builtin_amdgcn_mfma_f32_16x16x32_bf16(af[i], bfr[j], acc[i][j], 0, 0, 0);
  }

#pragma unroll
  for (int i = 0; i < 4; i++) {
    int row = bm + wr + i * 16 + lgrp * 4;
#pragma unroll
    for (int j = 0; j < 4; j++) {
      int col = bn + wc + j * 16 + lrow;
      float bv = bias[col];
#pragma unroll
      for (int r = 0; r < 4; r++) {
        float v = acc[i][j][r] + bv;
        if (OUTMODE == 0)
          ((unsigned short*)Cout)[(long)(row + r) * N + col] = f2bf(v);
        else
          ((float*)Cout)[(long)(row + r) * N + col] = v;
      }
    }
  }
}

__global__ __launch_bounds__(256) void gemm_qkv(
    const unsigned short* __restrict__ A, const unsigned short* __restrict__ Bq,
    const unsigned short* __restrict__ Bk, const unsigned short* __restrict__ Bv,
    const float* __restrict__ bq, const float* __restrict__ bk,
    const float* __restrict__ bv, unsigned short* __restrict__ Cq,
    unsigned short* __restrict__ Ck, unsigned short* __restrict__ Cv) {
  int z = blockIdx.z;
  const unsigned short* B = z == 0 ? Bq : (z == 1 ? Bk : Bv);
  const float* bias = z == 0 ? bq : (z == 1 ? bk : bv);
  unsigned short* C = z == 0 ? Cq : (z == 1 ? Ck : Cv);
  gemm_core<0>(A, B, bias, C, SEQ, DIM, DIM);
}

__global__ __launch_bounds__(256) void gemm_out(
    const unsigned short* __restrict__ A, const unsigned short* __restrict__ B,
    const float* __restrict__ bias, float* __restrict__ C) {
  gemm_core<1>(A, B, bias, C, SEQ, DIM, DIM);
}

// ---------------- RoPE (in place on bf16 Q,K) ----------------
__global__ void rope_kernel(unsigned short* __restrict__ Q,
                            unsigned short* __restrict__ Kt,
                            const float* __restrict__ cosT,
                            const float* __restrict__ sinT) {
  int idx = blockIdx.x * 256 + threadIdx.x;
  if (idx >= SEQ * NH * 40) return;
  int j = idx % 40;
  int t = idx / 40;
  int h = t & 15;
  int s = t >> 4;
  long base = (long)s * DIM + h * HD;
  float c0 = cosT[s * HD + j], s0 = sinT[s * HD + j];
  float c1 = cosT[s * HD + j + 40], s1 = sinT[s * HD + j + 40];
  float q0 = bf2f(Q[base + j]), q1 = bf2f(Q[base + j + 40]);
  Q[base + j] = f2bf(q0 * c0 - q1 * s0);
  Q[base + j + 40] = f2bf(q1 * c1 + q0 * s1);
  float k0 = bf2f(Kt[base + j]), k1 = bf2f(Kt[base + j + 40]);
  Kt[base + j] = f2bf(k0 * c0 - k1 * s0);
  Kt[base + j + 40] = f2bf(k1 * c1 + k0 * s1);
}

// ---------------- Flash attention v2: swapped QK^T, KVBLK=128 ----------------
// block = (head, segment, 64-row q tile); 4 waves, wave owns 16 q rows.
// S^T = mfma(K,Q): lane holds 32 keys for q-row = lane&15 -> local softmax.
__global__ __launch_bounds__(256) void attn_kernel(
    const unsigned short* __restrict__ Q, const unsigned short* __restrict__ K,
    const unsigned short* __restrict__ V, unsigned short* __restrict__ O,
    const int* __restrict__ cu) {
  const int h = blockIdx.x;
  const int g = blockIdx.y;
  const int qt = blockIdx.z;
  const int s0 = cu[g], s1 = cu[g + 1];
  const int qbase = s0 + qt * 64;
  if (qbase >= s1) return;

  __shared__ unsigned short vt[80 * 128];       // V^T, XOR-swizzled 8-elt granules
  __shared__ unsigned short ps[4 * 16 * 128];   // per-wave P, XOR-swizzled

  const int tid = threadIdx.x;
  const int wave = tid >> 6, lane = tid & 63;
  const int lrow = lane & 15, lgrp = lane >> 4;

  // Q fragments direct from global (B-operand: row = q = lrow)
  int qrow = qbase + wave * 16 + lrow;
  if (qrow > SEQ - 1) qrow = SEQ - 1;
  const unsigned short* qptr = Q + (long)qrow * DIM + h * HD;
  short8 aq[3];
#pragma unroll
  for (int ks = 0; ks < 3; ks++) {
    short8 z = {};
    if (ks < 2 || lgrp < 2) z = *(const short8*)(qptr + ks * 32 + lgrp * 8);
    aq[ks] = z;
  }

  f32x4 o_acc[5] = {};
  float m_r = -1e30f, l_r = 0.f;
  const float scale = 0.11180339887498949f;  // 1/sqrt(80)

  const int nk = (s1 - s0 + 127) / 128;
  for (int ck = 0; ck < nk; ck++) {
    const int kb = s0 + ck * 128;
    __syncthreads();  // prior iter's vt reads complete
    // stage V^T: coalesced short8 reads, swizzled scatter writes
#pragma unroll
    for (int p = 0; p < 5; p++) {
      int idx = p * 256 + tid;
      int row = idx / 10;            // key within chunk, 0..127
      int c0 = (idx - row * 10) * 8; // d base
      int srow = kb + row;
      if (srow > SEQ - 1) srow = SEQ - 1;
      short8 v8 = *(const short8*)(V + (long)srow * DIM + h * HD + c0);
#pragma unroll
      for (int j = 0; j < 8; j++) {
        int d = c0 + j;
        int phys = (row >> 3) ^ (d & 15);
        vt[d * 128 + phys * 8 + (row & 7)] = ((unsigned short*)&v8)[j];
      }
    }
    __syncthreads();

    // S^T = K * Q^T : sa[n] covers keys n*16 .. n*16+15 (row = key, col = q)
    f32x4 sa[8];
#pragma unroll
    for (int n = 0; n < 8; n++) sa[n] = (f32x4){0.f, 0.f, 0.f, 0.f};
#pragma unroll
    for (int n = 0; n < 8; n++) {
      const unsigned short* kp = K + (long)(kb + n * 16 + lrow) * DIM + h * HD;
#pragma unroll
      for (int ks = 0; ks < 3; ks++) {
        short8 kf = {};
        if (ks < 2 || lgrp < 2) kf = *(const short8*)(kp + ks * 32 + lgrp * 8);
        sa[n] = __builtin_amdgcn_mfma_f32_16x16x32_bf16(kf, aq[ks], sa[n], 0, 0, 0);
      }
    }

    // local softmax stats: lane holds keys n*16 + lgrp*4 + r for q = lrow
    float pm = -1e30f;
    float pv[8][4];
#pragma unroll
    for (int n = 0; n < 8; n++)
#pragma unroll
      for (int r = 0; r < 4; r++) {
        int key = kb + n * 16 + lgrp * 4 + r;
        float v = (key < s1) ? sa[n][r] * scale : -1e30f;
        pv[n][r] = v;
        pm = fmaxf(pm, v);
      }
    pm = fmaxf(pm, __shfl_xor(pm, 16));
    pm = fmaxf(pm, __shfl_xor(pm, 32));
    float mnew = fmaxf(m_r, pm);
    float sc = __expf(m_r - mnew);
    float ls = 0.f;
#pragma unroll
    for (int n = 0; n < 8; n++)
#pragma unroll
      for (int r = 0; r < 4; r++) {
        float e = __expf(pv[n][r] - mnew);
        pv[n][r] = e;
        ls += e;
      }
    ls += __shfl_xor(ls, 16);
    ls += __shfl_xor(ls, 32);
    l_r = l_r * sc + ls;
    m_r = mnew;

    // rescale o_acc: factor for q-row lgrp*4+r lives at lane lrow==that row
#pragma unroll
    for (int r = 0; r < 4; r++) {
      float scr = __shfl(sc, lgrp * 4 + r);
#pragma unroll
      for (int nf = 0; nf < 5; nf++) o_acc[nf][r] *= scr;
    }

    // P -> per-wave LDS (packed 4 bf16 = 8B per n-group), swizzled
#pragma unroll
    for (int n = 0; n < 8; n++) {
      unsigned lo = (unsigned)f2bf(pv[n][0]) | ((unsigned)f2bf(pv[n][1]) << 16);
      unsigned hi = (unsigned)f2bf(pv[n][2]) | ((unsigned)f2bf(pv[n][3]) << 16);
      int keybase = n * 16 + lgrp * 4;
      int phys = (keybase >> 3) ^ lrow;
      unsigned* dst = (unsigned*)&ps[wave * 2048 + lrow * 128 + phys * 8 + (keybase & 7)];
      dst[0] = lo;
      dst[1] = hi;
    }
    // no barrier: ps is per-wave, DS ops in-order within a wave

    // PV: o += P * V  (A = P rows=q, B = V^T rows=d)
#pragma unroll
    for (int ks = 0; ks < 4; ks++) {
      int g8 = ks * 4 + lgrp;
      short8 pf = *(const short8*)&ps[wave * 2048 + lrow * 128 + (g8 ^ lrow) * 8];
#pragma unroll
      for (int nf = 0; nf < 5; nf++) {
        short8 vf = *(const short8*)&vt[(nf * 16 + lrow) * 128 + (g8 ^ lrow) * 8];
        o_acc[nf] = __builtin_amdgcn_mfma_f32_16x16x32_bf16(pf, vf, o_acc[nf], 0, 0, 0);
      }
    }
  }

  // epilogue: normalize and write
#pragma unroll
  for (int r = 0; r < 4; r++) {
    float lr = __shfl(l_r, lgrp * 4 + r);
    float inv = 1.0f / lr;
    int row = qbase + wave * 16 + lgrp * 4 + r;
    if (row < s1) {
#pragma unroll
      for (int nf = 0; nf < 5; nf++)
        O[(long)row * DIM + h * HD + nf * 16 + lrow] = f2bf(o_acc[nf][r] * inv);
    }
  }
}

extern "C" void kernel_launch(void* const* d_in, const int* in_sizes, int n_in,
                              void* d_out, int out_size, void* d_ws, size_t ws_size,
                              hipStream_t stream) {
  const float* hs = (const float*)d_in[0];
  const float* Wq = (const float*)d_in[1];
  const float* bq = (const float*)d_in[2];
  const float* Wk = (const float*)d_in[3];
  const float* bk = (const float*)d_in[4];
  const float* Wv = (const float*)d_in[5];
  const float* bv = (const float*)d_in[6];
  const float* Wo = (const float*)d_in[7];
  const float* bo = (const float*)d_in[8];
  const float* cosT = (const float*)d_in[9];
  const float* sinT = (const float*)d_in[10];
  const int* cu = (const int*)d_in[11];
  const int nseg = in_sizes[11] - 1;  // 4

  char* ws = (char*)d_ws;
  unsigned short* hs_b = (unsigned short*)(ws);
  unsigned short* wq_b = (unsigned short*)(ws + 5242880);
  unsigned short* wk_b = (unsigned short*)(ws + 8519680);
  unsigned short* wv_b = (unsigned short*)(ws + 11796480);
  unsigned short* wo_b = (unsigned short*)(ws + 15073280);
  unsigned short* q_b  = (unsigned short*)(ws + 18350080);
  unsigned short* k_b  = (unsigned short*)(ws + 23592960);
  unsigned short* v_b  = (unsigned short*)(ws + 28835840);
  unsigned short* ao_b = (unsigned short*)(ws + 34078720);

  const int nh = SEQ * DIM;   // 2621440
  const int nw = DIM * DIM;   // 1638400
  cvt_f32_bf16<<<nh / 1024, 256, 0, stream>>>(hs, hs_b, nh);
  cvt_w4<<<dim3(nw / 1024, 4), 256, 0, stream>>>(Wq, Wk, Wv, Wo, wq_b, nw);

  dim3 gq(SEQ / 128, DIM / 128, 3);
  gemm_qkv<<<gq, 256, 0, stream>>>(hs_b, wq_b, wk_b, wv_b, bq, bk, bv, q_b, k_b, v_b);

  rope_kernel<<<(SEQ * NH * 40) / 256, 256, 0, stream>>>(q_b, k_b, cosT, sinT);

  dim3 ga(NH, nseg, (SEQ / nseg + 63) / 64);
  attn_kernel<<<ga, 256, 0, stream>>>(q_b, k_b, v_b, ao_b, cu);

  dim3 go(SEQ / 128, DIM / 128, 1);
  gemm_out<<<go, 256, 0, stream>>>(ao_b, wo_b, bo, (float*)d_out);
}